// Round 7
// baseline (2217.368 us; speedup 1.0000x reference)
//
#include <hip/hip_runtime.h>
#include <math.h>

#define N 4096
#define DIM 64
#define MAX_ITER 50
#define EPS 0.1f
#define INV_EPS 10.0f
#define THRESH 0.1f

// exp2/log2 domain constants
#define SV_SCALE 14.4269504088896340f  // INV_EPS * log2(e)
#define EPS_LN2 0.0693147180559945f    // EPS * ln(2)

// gfx950 native transcendentals: v_exp_f32 computes 2^x, v_log_f32 computes log2
#define EXP2F(x) __builtin_amdgcn_exp2f(x)
#define LOG2F(x) __builtin_amdgcn_logf(x)

// r4-winning geometry: 256 blocks x 1024 threads (16 waves), wave-per-row,
// 16 rows/block, 1 block/CU. launch_bounds(1024,4) -> VGPR<=128: full C row
// (16 float4 = 64 VGPR) lives in registers.
#define NBLK 256
#define TPB 1024
#define WAVES 16
#define NREP 16  // wake replicas

// ws layout (floats). All cross-block data accessed ONLY via relaxed
// agent-scope atomics (no cache-wide inv/wb ops -> C/Ct stay L2-resident).
#define WS_U 0
#define WS_V N
#define WS_FLAGS (2 * N)                  // 256 x (u32 gen, f32 val) 8B pairs
#define WS_GGEN (2 * N + 2 * NBLK)        // 16 replicas x 16-word stride
#define WS_TOTAL (2 * N + 2 * NBLK + NREP * 16)

// ---------------- init: zero u, v, flags, replicas ----------------
__global__ void init_ws(float* __restrict__ ws) {
    int i = blockIdx.x * 256 + threadIdx.x;
    if (i < WS_TOTAL) ws[i] = 0.0f;
}

// ---------------- build D[i][j] = sum_d (A[i][d]-B[j][d])^2 ----------------
__global__ __launch_bounds__(256) void build_dist(const float* __restrict__ A,
                                                  const float* __restrict__ B,
                                                  float* __restrict__ Dst) {
    __shared__ float As[64][68];
    __shared__ float Bs[64][68];
    const int i0 = blockIdx.y << 6, j0 = blockIdx.x << 6;
    const int t = threadIdx.x;
    const float* Ag = A + (size_t)i0 * DIM;
    const float* Bg = B + (size_t)j0 * DIM;
    for (int k = t; k < 4096; k += 256) {
        As[k >> 6][k & 63] = Ag[k];
        Bs[k >> 6][k & 63] = Bg[k];
    }
    __syncthreads();
    const int ty = t >> 4, tx = t & 15;
    float acc[4][4] = {{0.f}};
    for (int d = 0; d < DIM; d += 4) {
        float4 av[4], bv[4];
#pragma unroll
        for (int a = 0; a < 4; ++a) av[a] = *(const float4*)&As[ty + 16 * a][d];
#pragma unroll
        for (int b = 0; b < 4; ++b) bv[b] = *(const float4*)&Bs[tx + 16 * b][d];
#pragma unroll
        for (int a = 0; a < 4; ++a)
#pragma unroll
            for (int b = 0; b < 4; ++b) {
                float d0 = av[a].x - bv[b].x;
                float d1 = av[a].y - bv[b].y;
                float d2 = av[a].z - bv[b].z;
                float d3 = av[a].w - bv[b].w;
                acc[a][b] = fmaf(d0, d0, acc[a][b]);
                acc[a][b] = fmaf(d1, d1, acc[a][b]);
                acc[a][b] = fmaf(d2, d2, acc[a][b]);
                acc[a][b] = fmaf(d3, d3, acc[a][b]);
            }
    }
#pragma unroll
    for (int a = 0; a < 4; ++a) {
        int i = i0 + ty + 16 * a;
        float* drow = Dst + (size_t)i * N + j0;
#pragma unroll
        for (int b = 0; b < 4; ++b) drow[tx + 16 * b] = acc[a][b];
    }
}

// -------- grid barrier + NEXT-PHASE PREFETCH under the wait -----------------
// Arrive: one 8B relaxed-agent store (gen, blockPartial) per block. Block 0
// wave 0 scans all 256 flags, reduces payload, publishes to 16 replicas.
// The next phase's matrix row (static address!) is issued right after the
// entry __syncthreads -> its latency hides under flag propagation + poll;
// the exit __syncthreads drains it at near-zero residual cost.
__device__ __forceinline__ float grid_sync_pf(float* ws, int b, int t,
                                              unsigned G, const float* red2,
                                              float* bcast, bool wake,
                                              const float4* __restrict__ pf,
                                              float4 (&cR)[16], int lane) {
    __syncthreads();  // red2 complete; all compute stores retired
    if (pf) {
#pragma unroll
        for (int k = 0; k < 16; ++k) cR[k] = pf[lane + 64 * k];  // in flight
    }
    if (t == 0) {
        float s = 0.f;
#pragma unroll
        for (int i = 0; i < WAVES; ++i) s += red2[i];
        unsigned long long pk = (unsigned long long)G |
                                ((unsigned long long)__float_as_uint(s) << 32);
        __hip_atomic_store((unsigned long long*)(ws + WS_FLAGS) + b, pk,
                           __ATOMIC_RELAXED, __HIP_MEMORY_SCOPE_AGENT);
    }
    if (b == 0 && t < 64) {  // scanner wave
        unsigned long long* fl = (unsigned long long*)(ws + WS_FLAGS);
        float sum;
        for (;;) {
            bool ok = true;
            sum = 0.f;
#pragma unroll
            for (int j = 0; j < NBLK / 64; ++j) {
                unsigned long long q =
                    __hip_atomic_load(fl + (t * (NBLK / 64) + j),
                                      __ATOMIC_RELAXED, __HIP_MEMORY_SCOPE_AGENT);
                ok = ok && ((unsigned)q >= G);
                sum += __uint_as_float((unsigned)(q >> 32));
            }
            if (__all(ok)) break;
            __builtin_amdgcn_s_sleep(1);
        }
#pragma unroll
        for (int off = 32; off; off >>= 1) sum += __shfl_xor(sum, off);
        if (wake && t < NREP) {
            unsigned long long pk =
                (unsigned long long)G |
                ((unsigned long long)__float_as_uint(sum) << 32);
            __hip_atomic_store((unsigned long long*)(ws + WS_GGEN) + t * 8, pk,
                               __ATOMIC_RELAXED, __HIP_MEMORY_SCOPE_AGENT);
        }
        if (t == 0) *bcast = sum;
    } else if (t == 0 && wake) {  // b != 0
        unsigned long long* gp =
            (unsigned long long*)(ws + WS_GGEN) + (b & (NREP - 1)) * 8;
        unsigned long long q;
        for (;;) {
            q = __hip_atomic_load(gp, __ATOMIC_RELAXED, __HIP_MEMORY_SCOPE_AGENT);
            if ((unsigned)q >= G) break;
            __builtin_amdgcn_s_sleep(2);
        }
        *bcast = __uint_as_float((unsigned)(q >> 32));
    }
    __syncthreads();  // wake + drain prefetch (long since complete)
    return *bcast;    // valid when wake (all blocks) or b==0
}

// ------- stage a 4096-float vector into LDS, pre-scaled to exp2 domain -------
__device__ __forceinline__ void stage(const float* __restrict__ src,
                                      float* __restrict__ sv, int t) {
    const unsigned long long* s8 = (const unsigned long long*)src;
#pragma unroll
    for (int i = 0; i < 2; ++i) {
        int idx = t + TPB * i;  // 0..2047
        unsigned long long q = __hip_atomic_load(s8 + idx, __ATOMIC_RELAXED,
                                                 __HIP_MEMORY_SCOPE_AGENT);
        sv[2 * idx] = __uint_as_float((unsigned)q) * SV_SCALE;
        sv[2 * idx + 1] = __uint_as_float((unsigned)(q >> 32)) * SV_SCALE;
    }
}

// ------- one half-step: full row in registers, two-pass LSE in regs ---------
// d'_j = (v_j - C_ij)*10*log2e computed in place over cR (cR dead after).
// Pass 1: row max (register tree + 6 exp-free shuffles). Pass 2: sum 2^(d-m).
// un = target - EPS*ln2*(m + log2 s).
template <bool WERR>
__device__ __forceinline__ void phaseR(float4 (&cR)[16],
                                       const float* __restrict__ sv,
                                       float* __restrict__ dst, int row,
                                       int lane, int wv, float target,
                                       float* red2) {
    const float4* __restrict__ svv = (const float4*)sv;
    float old = 0.f;
    if (WERR && lane == 0)  // hoisted; overlaps the VALU work below
        old = __hip_atomic_load(&dst[row], __ATOMIC_RELAXED,
                                __HIP_MEMORY_SCOPE_AGENT);
#pragma unroll
    for (int k = 0; k < 16; ++k) {
        float4 w = svv[lane + 64 * k];
        cR[k].x = fmaf(cR[k].x, -SV_SCALE, w.x);
        cR[k].y = fmaf(cR[k].y, -SV_SCALE, w.y);
        cR[k].z = fmaf(cR[k].z, -SV_SCALE, w.z);
        cR[k].w = fmaf(cR[k].w, -SV_SCALE, w.w);
    }
    float ma = -3.0e38f, mb = -3.0e38f;
#pragma unroll
    for (int k = 0; k < 16; k += 2) {
        ma = fmaxf(ma, fmaxf(fmaxf(cR[k].x, cR[k].y), fmaxf(cR[k].z, cR[k].w)));
        mb = fmaxf(mb, fmaxf(fmaxf(cR[k + 1].x, cR[k + 1].y),
                             fmaxf(cR[k + 1].z, cR[k + 1].w)));
    }
    float m = fmaxf(ma, mb);
#pragma unroll
    for (int off = 32; off; off >>= 1) m = fmaxf(m, __shfl_xor(m, off));
    float s0 = 0.f, s1 = 0.f, s2 = 0.f, s3 = 0.f;
#pragma unroll
    for (int k = 0; k < 16; ++k) {
        s0 += EXP2F(cR[k].x - m);
        s1 += EXP2F(cR[k].y - m);
        s2 += EXP2F(cR[k].z - m);
        s3 += EXP2F(cR[k].w - m);
    }
    float s = (s0 + s1) + (s2 + s3);
#pragma unroll
    for (int off = 32; off; off >>= 1) s += __shfl_xor(s, off);
    float un = fmaf(-EPS_LN2, m + LOG2F(s), target);
    if (lane == 0) {
        red2[wv] = WERR ? fabsf(un - old) : 0.f;
        __hip_atomic_store(&dst[row], un, __ATOMIC_RELAXED,
                           __HIP_MEMORY_SCOPE_AGENT);
    }
}

// ---------------- persistent kernel: all iterations + final ----------------
__global__ __launch_bounds__(TPB, 4) void sinkhorn_persist(
    const float* __restrict__ Cm, const float* __restrict__ Ct,
    float* __restrict__ ws, float* __restrict__ out, float target) {
    __shared__ float sv[N];  // 16 KB staged (scaled) vector
    __shared__ float red2[WAVES];
    __shared__ float bcast;
    float* u = ws + WS_U;
    float* v = ws + WS_V;
    const int t = threadIdx.x;
    const int b = blockIdx.x;
    const int lane = t & 63, wv = t >> 6;
    const int row = (b << 4) + wv;  // this wave's row
    const float4* __restrict__ crow = (const float4*)(Cm + (size_t)row * N);
    const float4* __restrict__ ctrow = (const float4*)(Ct + (size_t)row * N);
    unsigned G = 1;
    float errv = 1e30f;

    // prologue: preload C row for iteration 0's u-phase
    float4 cR[16];
#pragma unroll
    for (int k = 0; k < 16; ++k) cR[k] = crow[lane + 64 * k];

    for (int it = 0; it < MAX_ITER; ++it) {
        stage(v, sv, t);
        __syncthreads();
        phaseR<true>(cR, sv, u, row, lane, wv, target, red2);
        errv = grid_sync_pf(ws, b, t, G++, red2, &bcast, true, ctrow, cR, lane);
        stage(u, sv, t);
        __syncthreads();
        phaseR<false>(cR, sv, v, row, lane, wv, target, red2);
        grid_sync_pf(ws, b, t, G++, red2, &bcast, true, crow, cR, lane);
        // reference latches done AFTER applying this iteration's updates.
        if (errv < THRESH) break;  // uniform: same published value everywhere
    }

    // ---- final: pi = exp((u_i + v_j - C_ij)/eps), cost = sum(pi*C) ----
    // cR holds this wave's C row (prefetched by the last grid_sync).
    // Ct (aliasing out[0..N^2)) is dead from here; pi writes may clobber it.
    stage(v, sv, t);  // scaled v
    __syncthreads();
    {
        float* pi = out + 1;
        float ui = 0.f;
        if (lane == 0)
            ui = __hip_atomic_load(&u[row], __ATOMIC_RELAXED,
                                   __HIP_MEMORY_SCOPE_AGENT);
        ui = __shfl(ui, 0) * SV_SCALE;  // exp2-domain
        float4* __restrict__ prow = (float4*)(pi + (size_t)row * N);
        const float4* __restrict__ svv = (const float4*)sv;
        float csum = 0.f;
#pragma unroll
        for (int k = 0; k < 16; ++k) {
            const int f = lane + 64 * k;
            float4 c = cR[k];
            float4 w = svv[f];
            float4 p;
            p.x = EXP2F(fmaf(c.x, -SV_SCALE, ui + w.x));
            p.y = EXP2F(fmaf(c.y, -SV_SCALE, ui + w.y));
            p.z = EXP2F(fmaf(c.z, -SV_SCALE, ui + w.z));
            p.w = EXP2F(fmaf(c.w, -SV_SCALE, ui + w.w));
            prow[f] = p;
            csum = fmaf(p.x, c.x, csum);
            csum = fmaf(p.y, c.y, csum);
            csum = fmaf(p.z, c.z, csum);
            csum = fmaf(p.w, c.w, csum);
        }
#pragma unroll
        for (int off = 32; off; off >>= 1) csum += __shfl_xor(csum, off);
        if (lane == 0) red2[wv] = csum;
    }
    // cost rides the final barrier payload; only the scanner needs the total.
    float ctot =
        grid_sync_pf(ws, b, t, G++, red2, &bcast, false, nullptr, cR, lane);
    if (b == 0 && t == 0) out[0] = ctot;
}

extern "C" void kernel_launch(void* const* d_in, const int* in_sizes, int n_in,
                              void* d_out, int out_size, void* d_ws, size_t ws_size,
                              hipStream_t stream) {
    const float* x = (const float*)d_in[0];  // [4096,64]
    const float* y = (const float*)d_in[1];  // [4096,64]
    float* out = (float*)d_out;              // [0]=cost, [1..N*N]=pi, [1+N*N..]=C
    float* C = out + 1 + (size_t)N * N;
    float* Ct = out;  // scratch: aliases cost+pi region, dead before final writes
    float* ws = (float*)d_ws;

    init_ws<<<dim3((WS_TOTAL + 255) / 256), dim3(256), 0, stream>>>(ws);

    dim3 bgrid(64, 64);
    build_dist<<<bgrid, dim3(256), 0, stream>>>(x, y, C);   // C[i][j]
    build_dist<<<bgrid, dim3(256), 0, stream>>>(y, x, Ct);  // C^T[j][i]

    float target = EPS * logf(1.0f / (float)N + 1e-8f);  // == eps*log_mu == eps*log_nu

    sinkhorn_persist<<<dim3(NBLK), dim3(TPB), 0, stream>>>(C, Ct, ws, out, target);
}

// Round 8
// 2215.484 us; speedup vs baseline: 1.0009x; 1.0009x over previous
//
#include <hip/hip_runtime.h>
#include <math.h>

#define N 4096
#define DIM 64
#define MAX_ITER 50
#define EPS 0.1f
#define INV_EPS 10.0f
#define THRESH 0.1f

// exp2/log2 domain constants
#define SV_SCALE 14.4269504088896340f  // INV_EPS * log2(e)
#define EPS_LN2 0.0693147180559945f    // EPS * ln(2)

// gfx950 native transcendentals: v_exp_f32 computes 2^x, v_log_f32 computes log2
#define EXP2F(x) __builtin_amdgcn_exp2f(x)
#define LOG2F(x) __builtin_amdgcn_logf(x)

// Geometry: 256 blocks x 1024 threads (16 waves), wave-per-row, 16 rows/block,
// 1 block/CU. CRITICAL: amdgpu_waves_per_eu(4,4) pins the register allocator
// to exactly 4 waves/EU (16 waves/CU) -> full 128-VGPR budget. Without it the
// compiler shrinks to 64 VGPR chasing a 2-blocks/CU tier that can't exist
// (grid == 1 block/CU), rematerializing cR[16] as global re-loads (r7: 3x FETCH).
#define NBLK 256
#define TPB 1024
#define WAVES 16
#define NREP 16  // wake replicas

// ws layout (floats). All cross-block data accessed ONLY via relaxed
// agent-scope atomics (no cache-wide inv/wb ops -> C/Ct stay L2-resident).
#define WS_U 0
#define WS_V N
#define WS_FLAGS (2 * N)                  // 256 x (u32 gen, f32 val) 8B pairs
#define WS_GGEN (2 * N + 2 * NBLK)        // 16 replicas x 16-word stride
#define WS_TOTAL (2 * N + 2 * NBLK + NREP * 16)

// ---------------- init: zero u, v, flags, replicas ----------------
__global__ void init_ws(float* __restrict__ ws) {
    int i = blockIdx.x * 256 + threadIdx.x;
    if (i < WS_TOTAL) ws[i] = 0.0f;
}

// ---------------- build D[i][j] = sum_d (A[i][d]-B[j][d])^2 ----------------
__global__ __launch_bounds__(256) void build_dist(const float* __restrict__ A,
                                                  const float* __restrict__ B,
                                                  float* __restrict__ Dst) {
    __shared__ float As[64][68];
    __shared__ float Bs[64][68];
    const int i0 = blockIdx.y << 6, j0 = blockIdx.x << 6;
    const int t = threadIdx.x;
    const float* Ag = A + (size_t)i0 * DIM;
    const float* Bg = B + (size_t)j0 * DIM;
    for (int k = t; k < 4096; k += 256) {
        As[k >> 6][k & 63] = Ag[k];
        Bs[k >> 6][k & 63] = Bg[k];
    }
    __syncthreads();
    const int ty = t >> 4, tx = t & 15;
    float acc[4][4] = {{0.f}};
    for (int d = 0; d < DIM; d += 4) {
        float4 av[4], bv[4];
#pragma unroll
        for (int a = 0; a < 4; ++a) av[a] = *(const float4*)&As[ty + 16 * a][d];
#pragma unroll
        for (int b = 0; b < 4; ++b) bv[b] = *(const float4*)&Bs[tx + 16 * b][d];
#pragma unroll
        for (int a = 0; a < 4; ++a)
#pragma unroll
            for (int b = 0; b < 4; ++b) {
                float d0 = av[a].x - bv[b].x;
                float d1 = av[a].y - bv[b].y;
                float d2 = av[a].z - bv[b].z;
                float d3 = av[a].w - bv[b].w;
                acc[a][b] = fmaf(d0, d0, acc[a][b]);
                acc[a][b] = fmaf(d1, d1, acc[a][b]);
                acc[a][b] = fmaf(d2, d2, acc[a][b]);
                acc[a][b] = fmaf(d3, d3, acc[a][b]);
            }
    }
#pragma unroll
    for (int a = 0; a < 4; ++a) {
        int i = i0 + ty + 16 * a;
        float* drow = Dst + (size_t)i * N + j0;
#pragma unroll
        for (int b = 0; b < 4; ++b) drow[tx + 16 * b] = acc[a][b];
    }
}

// -------- grid barrier + NEXT-PHASE PREFETCH under the wait -----------------
// Arrive: one 8B relaxed-agent store (gen, blockPartial) per block. Block 0
// wave 0 scans all 256 flags, reduces payload, publishes to 16 replicas.
// The next phase's matrix row (static address!) is issued right after the
// entry __syncthreads -> its latency hides under flag propagation + poll;
// the exit __syncthreads drains it at near-zero residual cost.
__device__ __forceinline__ float grid_sync_pf(float* ws, int b, int t,
                                              unsigned G, const float* red2,
                                              float* bcast, bool wake,
                                              const float4* __restrict__ pf,
                                              float4 (&cR)[16], int lane) {
    __syncthreads();  // red2 complete; all compute stores retired
    if (pf) {
#pragma unroll
        for (int k = 0; k < 16; ++k) cR[k] = pf[lane + 64 * k];  // in flight
    }
    if (t == 0) {
        float s = 0.f;
#pragma unroll
        for (int i = 0; i < WAVES; ++i) s += red2[i];
        unsigned long long pk = (unsigned long long)G |
                                ((unsigned long long)__float_as_uint(s) << 32);
        __hip_atomic_store((unsigned long long*)(ws + WS_FLAGS) + b, pk,
                           __ATOMIC_RELAXED, __HIP_MEMORY_SCOPE_AGENT);
    }
    if (b == 0 && t < 64) {  // scanner wave
        unsigned long long* fl = (unsigned long long*)(ws + WS_FLAGS);
        float sum;
        for (;;) {
            bool ok = true;
            sum = 0.f;
#pragma unroll
            for (int j = 0; j < NBLK / 64; ++j) {
                unsigned long long q =
                    __hip_atomic_load(fl + (t * (NBLK / 64) + j),
                                      __ATOMIC_RELAXED, __HIP_MEMORY_SCOPE_AGENT);
                ok = ok && ((unsigned)q >= G);
                sum += __uint_as_float((unsigned)(q >> 32));
            }
            if (__all(ok)) break;
            __builtin_amdgcn_s_sleep(1);
        }
#pragma unroll
        for (int off = 32; off; off >>= 1) sum += __shfl_xor(sum, off);
        if (wake && t < NREP) {
            unsigned long long pk =
                (unsigned long long)G |
                ((unsigned long long)__float_as_uint(sum) << 32);
            __hip_atomic_store((unsigned long long*)(ws + WS_GGEN) + t * 8, pk,
                               __ATOMIC_RELAXED, __HIP_MEMORY_SCOPE_AGENT);
        }
        if (t == 0) *bcast = sum;
    } else if (t == 0 && wake) {  // b != 0
        unsigned long long* gp =
            (unsigned long long*)(ws + WS_GGEN) + (b & (NREP - 1)) * 8;
        unsigned long long q;
        for (;;) {
            q = __hip_atomic_load(gp, __ATOMIC_RELAXED, __HIP_MEMORY_SCOPE_AGENT);
            if ((unsigned)q >= G) break;
            __builtin_amdgcn_s_sleep(2);
        }
        *bcast = __uint_as_float((unsigned)(q >> 32));
    }
    __syncthreads();  // wake + drain prefetch (long since complete)
    return *bcast;    // valid when wake (all blocks) or b==0
}

// ------- stage a 4096-float vector into LDS, pre-scaled to exp2 domain -------
__device__ __forceinline__ void stage(const float* __restrict__ src,
                                      float* __restrict__ sv, int t) {
    const unsigned long long* s8 = (const unsigned long long*)src;
#pragma unroll
    for (int i = 0; i < 2; ++i) {
        int idx = t + TPB * i;  // 0..2047
        unsigned long long q = __hip_atomic_load(s8 + idx, __ATOMIC_RELAXED,
                                                 __HIP_MEMORY_SCOPE_AGENT);
        sv[2 * idx] = __uint_as_float((unsigned)q) * SV_SCALE;
        sv[2 * idx + 1] = __uint_as_float((unsigned)(q >> 32)) * SV_SCALE;
    }
}

// ------- one half-step: full row in registers, two-pass LSE in regs ---------
// d'_j = (v_j - C_ij)*10*log2e computed in place over cR (cR dead after).
// Pass 1: row max (register tree + 6 exp-free shuffles). Pass 2: sum 2^(d-m).
// un = target - EPS*ln2*(m + log2 s).
template <bool WERR>
__device__ __forceinline__ void phaseR(float4 (&cR)[16],
                                       const float* __restrict__ sv,
                                       float* __restrict__ dst, int row,
                                       int lane, int wv, float target,
                                       float* red2) {
    const float4* __restrict__ svv = (const float4*)sv;
    float old = 0.f;
    if (WERR && lane == 0)  // hoisted; overlaps the VALU work below
        old = __hip_atomic_load(&dst[row], __ATOMIC_RELAXED,
                                __HIP_MEMORY_SCOPE_AGENT);
#pragma unroll
    for (int k = 0; k < 16; ++k) {
        float4 w = svv[lane + 64 * k];
        cR[k].x = fmaf(cR[k].x, -SV_SCALE, w.x);
        cR[k].y = fmaf(cR[k].y, -SV_SCALE, w.y);
        cR[k].z = fmaf(cR[k].z, -SV_SCALE, w.z);
        cR[k].w = fmaf(cR[k].w, -SV_SCALE, w.w);
    }
    float ma = -3.0e38f, mb = -3.0e38f;
#pragma unroll
    for (int k = 0; k < 16; k += 2) {
        ma = fmaxf(ma, fmaxf(fmaxf(cR[k].x, cR[k].y), fmaxf(cR[k].z, cR[k].w)));
        mb = fmaxf(mb, fmaxf(fmaxf(cR[k + 1].x, cR[k + 1].y),
                             fmaxf(cR[k + 1].z, cR[k + 1].w)));
    }
    float m = fmaxf(ma, mb);
#pragma unroll
    for (int off = 32; off; off >>= 1) m = fmaxf(m, __shfl_xor(m, off));
    float s0 = 0.f, s1 = 0.f, s2 = 0.f, s3 = 0.f;
#pragma unroll
    for (int k = 0; k < 16; ++k) {
        s0 += EXP2F(cR[k].x - m);
        s1 += EXP2F(cR[k].y - m);
        s2 += EXP2F(cR[k].z - m);
        s3 += EXP2F(cR[k].w - m);
    }
    float s = (s0 + s1) + (s2 + s3);
#pragma unroll
    for (int off = 32; off; off >>= 1) s += __shfl_xor(s, off);
    float un = fmaf(-EPS_LN2, m + LOG2F(s), target);
    if (lane == 0) {
        red2[wv] = WERR ? fabsf(un - old) : 0.f;
        __hip_atomic_store(&dst[row], un, __ATOMIC_RELAXED,
                           __HIP_MEMORY_SCOPE_AGENT);
    }
}

// ---------------- persistent kernel: all iterations + final ----------------
__global__ __launch_bounds__(TPB)
__attribute__((amdgpu_waves_per_eu(4, 4)))  // pin 4 waves/EU -> 128 VGPR budget
void sinkhorn_persist(
    const float* __restrict__ Cm, const float* __restrict__ Ct,
    float* __restrict__ ws, float* __restrict__ out, float target) {
    __shared__ float sv[N];  // 16 KB staged (scaled) vector
    __shared__ float red2[WAVES];
    __shared__ float bcast;
    float* u = ws + WS_U;
    float* v = ws + WS_V;
    const int t = threadIdx.x;
    const int b = blockIdx.x;
    const int lane = t & 63, wv = t >> 6;
    const int row = (b << 4) + wv;  // this wave's row
    const float4* __restrict__ crow = (const float4*)(Cm + (size_t)row * N);
    const float4* __restrict__ ctrow = (const float4*)(Ct + (size_t)row * N);
    unsigned G = 1;
    float errv = 1e30f;

    // prologue: preload C row for iteration 0's u-phase
    float4 cR[16];
#pragma unroll
    for (int k = 0; k < 16; ++k) cR[k] = crow[lane + 64 * k];

    for (int it = 0; it < MAX_ITER; ++it) {
        stage(v, sv, t);
        __syncthreads();
        phaseR<true>(cR, sv, u, row, lane, wv, target, red2);
        errv = grid_sync_pf(ws, b, t, G++, red2, &bcast, true, ctrow, cR, lane);
        stage(u, sv, t);
        __syncthreads();
        phaseR<false>(cR, sv, v, row, lane, wv, target, red2);
        grid_sync_pf(ws, b, t, G++, red2, &bcast, true, crow, cR, lane);
        // reference latches done AFTER applying this iteration's updates.
        if (errv < THRESH) break;  // uniform: same published value everywhere
    }

    // ---- final: pi = exp((u_i + v_j - C_ij)/eps), cost = sum(pi*C) ----
    // cR holds this wave's C row (prefetched by the last grid_sync).
    // Ct (aliasing out[0..N^2)) is dead from here; pi writes may clobber it.
    stage(v, sv, t);  // scaled v
    __syncthreads();
    {
        float* pi = out + 1;
        float ui = 0.f;
        if (lane == 0)
            ui = __hip_atomic_load(&u[row], __ATOMIC_RELAXED,
                                   __HIP_MEMORY_SCOPE_AGENT);
        ui = __shfl(ui, 0) * SV_SCALE;  // exp2-domain
        float4* __restrict__ prow = (float4*)(pi + (size_t)row * N);
        const float4* __restrict__ svv = (const float4*)sv;
        float csum = 0.f;
#pragma unroll
        for (int k = 0; k < 16; ++k) {
            const int f = lane + 64 * k;
            float4 c = cR[k];
            float4 w = svv[f];
            float4 p;
            p.x = EXP2F(fmaf(c.x, -SV_SCALE, ui + w.x));
            p.y = EXP2F(fmaf(c.y, -SV_SCALE, ui + w.y));
            p.z = EXP2F(fmaf(c.z, -SV_SCALE, ui + w.z));
            p.w = EXP2F(fmaf(c.w, -SV_SCALE, ui + w.w));
            prow[f] = p;
            csum = fmaf(p.x, c.x, csum);
            csum = fmaf(p.y, c.y, csum);
            csum = fmaf(p.z, c.z, csum);
            csum = fmaf(p.w, c.w, csum);
        }
#pragma unroll
        for (int off = 32; off; off >>= 1) csum += __shfl_xor(csum, off);
        if (lane == 0) red2[wv] = csum;
    }
    // cost rides the final barrier payload; only the scanner needs the total.
    float ctot =
        grid_sync_pf(ws, b, t, G++, red2, &bcast, false, nullptr, cR, lane);
    if (b == 0 && t == 0) out[0] = ctot;
}

extern "C" void kernel_launch(void* const* d_in, const int* in_sizes, int n_in,
                              void* d_out, int out_size, void* d_ws, size_t ws_size,
                              hipStream_t stream) {
    const float* x = (const float*)d_in[0];  // [4096,64]
    const float* y = (const float*)d_in[1];  // [4096,64]
    float* out = (float*)d_out;              // [0]=cost, [1..N*N]=pi, [1+N*N..]=C
    float* C = out + 1 + (size_t)N * N;
    float* Ct = out;  // scratch: aliases cost+pi region, dead before final writes
    float* ws = (float*)d_ws;

    init_ws<<<dim3((WS_TOTAL + 255) / 256), dim3(256), 0, stream>>>(ws);

    dim3 bgrid(64, 64);
    build_dist<<<bgrid, dim3(256), 0, stream>>>(x, y, C);   // C[i][j]
    build_dist<<<bgrid, dim3(256), 0, stream>>>(y, x, Ct);  // C^T[j][i]

    float target = EPS * logf(1.0f / (float)N + 1e-8f);  // == eps*log_mu == eps*log_nu

    sinkhorn_persist<<<dim3(NBLK), dim3(TPB), 0, stream>>>(C, Ct, ws, out, target);
}

// Round 9
// 1530.722 us; speedup vs baseline: 1.4486x; 1.4473x over previous
//
#include <hip/hip_runtime.h>
#include <math.h>

#define N 4096
#define DIM 64
#define MAX_ITER 50
#define EPS 0.1f
#define INV_EPS 10.0f
#define THRESH 0.1f

// exp2/log2 domain constants
#define SV_SCALE 14.4269504088896340f  // INV_EPS * log2(e)
#define EPS_LN2 0.0693147180559945f    // EPS * ln(2)

// gfx950 native transcendentals: v_exp_f32 computes 2^x, v_log_f32 computes log2
#define EXP2F(x) __builtin_amdgcn_exp2f(x)
#define LOG2F(x) __builtin_amdgcn_logf(x)

// Geometry: 256 blocks x 1024 threads (16 waves), wave-per-row, 16 rows/block,
// 1 block/CU. Each wave PINS its 16KB C row in 64 VGPRs for the entire kernel
// (asm keep-alive defeats rematerialization; waves_per_eu(4,4) authorizes the
// 128-VGPR tier). u-phase streams ZERO C bytes; only the v-phase streams Ct.
#define NBLK 256
#define TPB 1024
#define WAVES 16
#define NREP 16  // wake replicas

// ws layout (floats). All cross-block data accessed ONLY via relaxed
// agent-scope atomics (no cache-wide inv/wb ops -> Ct stays cacheable).
#define WS_U 0
#define WS_V N
#define WS_FLAGS (2 * N)                  // 256 x (u32 gen, f32 val) 8B pairs
#define WS_GGEN (2 * N + 2 * NBLK)        // 16 replicas x 16-word stride
#define WS_TOTAL (2 * N + 2 * NBLK + NREP * 16)

// opaque keep-alive: values become non-rematerializable register residents
#define PIN4(v) asm volatile("" : "+v"(v.x), "+v"(v.y), "+v"(v.z), "+v"(v.w))

// ---------------- init: zero u, v, flags, replicas ----------------
__global__ void init_ws(float* __restrict__ ws) {
    int i = blockIdx.x * 256 + threadIdx.x;
    if (i < WS_TOTAL) ws[i] = 0.0f;
}

// ---------------- build D[i][j] = sum_d (A[i][d]-B[j][d])^2 ----------------
__global__ __launch_bounds__(256) void build_dist(const float* __restrict__ A,
                                                  const float* __restrict__ B,
                                                  float* __restrict__ Dst) {
    __shared__ float As[64][68];
    __shared__ float Bs[64][68];
    const int i0 = blockIdx.y << 6, j0 = blockIdx.x << 6;
    const int t = threadIdx.x;
    const float* Ag = A + (size_t)i0 * DIM;
    const float* Bg = B + (size_t)j0 * DIM;
    for (int k = t; k < 4096; k += 256) {
        As[k >> 6][k & 63] = Ag[k];
        Bs[k >> 6][k & 63] = Bg[k];
    }
    __syncthreads();
    const int ty = t >> 4, tx = t & 15;
    float acc[4][4] = {{0.f}};
    for (int d = 0; d < DIM; d += 4) {
        float4 av[4], bv[4];
#pragma unroll
        for (int a = 0; a < 4; ++a) av[a] = *(const float4*)&As[ty + 16 * a][d];
#pragma unroll
        for (int b = 0; b < 4; ++b) bv[b] = *(const float4*)&Bs[tx + 16 * b][d];
#pragma unroll
        for (int a = 0; a < 4; ++a)
#pragma unroll
            for (int b = 0; b < 4; ++b) {
                float d0 = av[a].x - bv[b].x;
                float d1 = av[a].y - bv[b].y;
                float d2 = av[a].z - bv[b].z;
                float d3 = av[a].w - bv[b].w;
                acc[a][b] = fmaf(d0, d0, acc[a][b]);
                acc[a][b] = fmaf(d1, d1, acc[a][b]);
                acc[a][b] = fmaf(d2, d2, acc[a][b]);
                acc[a][b] = fmaf(d3, d3, acc[a][b]);
            }
    }
#pragma unroll
    for (int a = 0; a < 4; ++a) {
        int i = i0 + ty + 16 * a;
        float* drow = Dst + (size_t)i * N + j0;
#pragma unroll
        for (int b = 0; b < 4; ++b) drow[tx + 16 * b] = acc[a][b];
    }
}

// -------- grid barrier: flag-array + dedicated scanner, payload-carrying -----
// (r4-proven) Arrive: one 8B relaxed-agent store (gen, blockPartial) per block.
// Block 0 wave 0 scans all 256 flags, reduces payload, publishes to 16
// replicas. Others poll their replica. Entry __syncthreads orders prior stores.
__device__ __forceinline__ float grid_sync(float* ws, int b, int t, unsigned G,
                                           const float* red2, float* bcast,
                                           bool wake) {
    __syncthreads();  // red2 complete; all compute stores retired
    if (t == 0) {
        float s = 0.f;
#pragma unroll
        for (int i = 0; i < WAVES; ++i) s += red2[i];
        unsigned long long pk = (unsigned long long)G |
                                ((unsigned long long)__float_as_uint(s) << 32);
        __hip_atomic_store((unsigned long long*)(ws + WS_FLAGS) + b, pk,
                           __ATOMIC_RELAXED, __HIP_MEMORY_SCOPE_AGENT);
    }
    if (b == 0 && t < 64) {  // scanner wave
        unsigned long long* fl = (unsigned long long*)(ws + WS_FLAGS);
        float sum;
        for (;;) {
            bool ok = true;
            sum = 0.f;
#pragma unroll
            for (int j = 0; j < NBLK / 64; ++j) {
                unsigned long long q =
                    __hip_atomic_load(fl + (t * (NBLK / 64) + j),
                                      __ATOMIC_RELAXED, __HIP_MEMORY_SCOPE_AGENT);
                ok = ok && ((unsigned)q >= G);
                sum += __uint_as_float((unsigned)(q >> 32));
            }
            if (__all(ok)) break;
            __builtin_amdgcn_s_sleep(1);
        }
#pragma unroll
        for (int off = 32; off; off >>= 1) sum += __shfl_xor(sum, off);
        if (wake && t < NREP) {
            unsigned long long pk =
                (unsigned long long)G |
                ((unsigned long long)__float_as_uint(sum) << 32);
            __hip_atomic_store((unsigned long long*)(ws + WS_GGEN) + t * 8, pk,
                               __ATOMIC_RELAXED, __HIP_MEMORY_SCOPE_AGENT);
        }
        if (t == 0) *bcast = sum;
    } else if (t == 0 && wake) {  // b != 0
        unsigned long long* gp =
            (unsigned long long*)(ws + WS_GGEN) + (b & (NREP - 1)) * 8;
        unsigned long long q;
        for (;;) {
            q = __hip_atomic_load(gp, __ATOMIC_RELAXED, __HIP_MEMORY_SCOPE_AGENT);
            if ((unsigned)q >= G) break;
            __builtin_amdgcn_s_sleep(2);
        }
        *bcast = __uint_as_float((unsigned)(q >> 32));
    }
    __syncthreads();
    return *bcast;  // valid when wake (all blocks) or b==0
}

// ------- stage a 4096-float vector into LDS, pre-scaled to exp2 domain -------
__device__ __forceinline__ void stage(const float* __restrict__ src,
                                      float* __restrict__ sv, int t) {
    const unsigned long long* s8 = (const unsigned long long*)src;
#pragma unroll
    for (int i = 0; i < 2; ++i) {
        int idx = t + TPB * i;  // 0..2047
        unsigned long long q = __hip_atomic_load(s8 + idx, __ATOMIC_RELAXED,
                                                 __HIP_MEMORY_SCOPE_AGENT);
        sv[2 * idx] = __uint_as_float((unsigned)q) * SV_SCALE;
        sv[2 * idx + 1] = __uint_as_float((unsigned)(q >> 32)) * SV_SCALE;
    }
}

// ---- u-phase: row LSE from the PINNED register row (zero memory traffic) ----
// Online LSE over 4 groups of 16 elems; cR is read-only (reused every iter).
__device__ __forceinline__ void phasePinned(const float4 (&cR)[16],
                                            const float* __restrict__ sv,
                                            float* __restrict__ dst, int row,
                                            int lane, int wv, float target,
                                            float* red2) {
    const float4* __restrict__ svv = (const float4*)sv;
    float old = 0.f;
    if (lane == 0)
        old = __hip_atomic_load(&dst[row], __ATOMIC_RELAXED,
                                __HIP_MEMORY_SCOPE_AGENT);
    float m = -3.0e38f, s = 0.f;
#pragma unroll
    for (int g = 0; g < 4; ++g) {
        float d[16];
#pragma unroll
        for (int k = 0; k < 4; ++k) {
            float4 w = svv[lane + 64 * (4 * g + k)];
            d[4 * k + 0] = fmaf(cR[4 * g + k].x, -SV_SCALE, w.x);
            d[4 * k + 1] = fmaf(cR[4 * g + k].y, -SV_SCALE, w.y);
            d[4 * k + 2] = fmaf(cR[4 * g + k].z, -SV_SCALE, w.z);
            d[4 * k + 3] = fmaf(cR[4 * g + k].w, -SV_SCALE, w.w);
        }
        float m4[4];
#pragma unroll
        for (int k = 0; k < 4; ++k)
            m4[k] = fmaxf(fmaxf(d[4 * k], d[4 * k + 1]),
                          fmaxf(d[4 * k + 2], d[4 * k + 3]));
        float mg = fmaxf(fmaxf(m4[0], m4[1]), fmaxf(m4[2], m4[3]));
        float mn = fmaxf(m, mg);
        float ps = 0.f;
#pragma unroll
        for (int k = 0; k < 16; ++k) ps += EXP2F(d[k] - mn);
        s = fmaf(s, EXP2F(m - mn), ps);
        m = mn;
    }
#pragma unroll
    for (int off = 32; off; off >>= 1) {
        float mo = __shfl_xor(m, off);
        float so = __shfl_xor(s, off);
        float mn = fmaxf(m, mo);
        s = fmaf(s, EXP2F(m - mn), so * EXP2F(mo - mn));
        m = mn;
    }
    float un = fmaf(-EPS_LN2, m + LOG2F(s), target);
    if (lane == 0) {
        red2[wv] = fabsf(un - old);
        __hip_atomic_store(&dst[row], un, __ATOMIC_RELAXED,
                           __HIP_MEMORY_SCOPE_AGENT);
    }
}

// ---- v-phase: stream the Ct row, load-once online LSE (r4-proven shape) ----
__device__ __forceinline__ void phaseStream(const float4* __restrict__ rowp,
                                            const float* __restrict__ sv,
                                            float* __restrict__ dst, int row,
                                            int lane, int wv, float target,
                                            float* red2) {
    const float4* __restrict__ svv = (const float4*)sv;
    float m = -3.0e38f, s = 0.f;
#pragma unroll
    for (int g = 0; g < 4; ++g) {
        float4 c[4], w[4];
#pragma unroll
        for (int k = 0; k < 4; ++k) {
            const int f = lane + 64 * (4 * g + k);
            c[k] = rowp[f];
            w[k] = svv[f];
        }
        float d[16];
#pragma unroll
        for (int k = 0; k < 4; ++k) {
            d[4 * k + 0] = fmaf(c[k].x, -SV_SCALE, w[k].x);
            d[4 * k + 1] = fmaf(c[k].y, -SV_SCALE, w[k].y);
            d[4 * k + 2] = fmaf(c[k].z, -SV_SCALE, w[k].z);
            d[4 * k + 3] = fmaf(c[k].w, -SV_SCALE, w[k].w);
        }
        float m4[4];
#pragma unroll
        for (int k = 0; k < 4; ++k)
            m4[k] = fmaxf(fmaxf(d[4 * k], d[4 * k + 1]),
                          fmaxf(d[4 * k + 2], d[4 * k + 3]));
        float mg = fmaxf(fmaxf(m4[0], m4[1]), fmaxf(m4[2], m4[3]));
        float mn = fmaxf(m, mg);
        float ps = 0.f;
#pragma unroll
        for (int k = 0; k < 16; ++k) ps += EXP2F(d[k] - mn);
        s = fmaf(s, EXP2F(m - mn), ps);
        m = mn;
    }
#pragma unroll
    for (int off = 32; off; off >>= 1) {
        float mo = __shfl_xor(m, off);
        float so = __shfl_xor(s, off);
        float mn = fmaxf(m, mo);
        s = fmaf(s, EXP2F(m - mn), so * EXP2F(mo - mn));
        m = mn;
    }
    float un = fmaf(-EPS_LN2, m + LOG2F(s), target);
    if (lane == 0) {
        red2[wv] = 0.f;
        __hip_atomic_store(&dst[row], un, __ATOMIC_RELAXED,
                           __HIP_MEMORY_SCOPE_AGENT);
    }
}

// ---------------- persistent kernel: all iterations + final ----------------
__global__ __launch_bounds__(TPB)
__attribute__((amdgpu_waves_per_eu(4, 4)))  // authorize the 128-VGPR tier
void sinkhorn_persist(
    const float* __restrict__ Cm, const float* __restrict__ Ct,
    float* __restrict__ ws, float* __restrict__ out, float target) {
    __shared__ float sv[N];  // 16 KB staged (scaled) vector
    __shared__ float red2[WAVES];
    __shared__ float bcast;
    float* u = ws + WS_U;
    float* v = ws + WS_V;
    const int t = threadIdx.x;
    const int b = blockIdx.x;
    const int lane = t & 63, wv = t >> 6;
    const int row = (b << 4) + wv;  // this wave's row
    const float4* __restrict__ ctrow = (const float4*)(Ct + (size_t)row * N);
    unsigned G = 1;
    float errv = 1e30f;

    // prologue: load this wave's C row ONCE; pin it in 64 VGPRs for the whole
    // kernel (asm keep-alive -> cannot be rematerialized as later reloads).
    float4 cR[16];
    {
        const float4* __restrict__ crow = (const float4*)(Cm + (size_t)row * N);
#pragma unroll
        for (int k = 0; k < 16; ++k) cR[k] = crow[lane + 64 * k];
#pragma unroll
        for (int k = 0; k < 16; ++k) PIN4(cR[k]);
    }

    for (int it = 0; it < MAX_ITER; ++it) {
        stage(v, sv, t);
        __syncthreads();
        phasePinned(cR, sv, u, row, lane, wv, target, red2);  // 0 C bytes
        errv = grid_sync(ws, b, t, G++, red2, &bcast, true);  // total err
        stage(u, sv, t);
        __syncthreads();
        phaseStream(ctrow, sv, v, row, lane, wv, target, red2);  // stream Ct
        grid_sync(ws, b, t, G++, red2, &bcast, true);
        // reference latches done AFTER applying this iteration's updates.
        if (errv < THRESH) break;  // uniform: same published value everywhere
    }

    // ---- final: pi = exp((u_i + v_j - C_ij)/eps), cost = sum(pi*C) ----
    // cR holds this wave's C row. Ct (aliasing out[0..N^2)) is dead from
    // here; pi writes may clobber it.
    stage(v, sv, t);  // scaled v
    __syncthreads();
    {
        float* pi = out + 1;
        float ui = 0.f;
        if (lane == 0)
            ui = __hip_atomic_load(&u[row], __ATOMIC_RELAXED,
                                   __HIP_MEMORY_SCOPE_AGENT);
        ui = __shfl(ui, 0) * SV_SCALE;  // exp2-domain
        float4* __restrict__ prow = (float4*)(pi + (size_t)row * N);
        const float4* __restrict__ svv = (const float4*)sv;
        float csum = 0.f;
#pragma unroll
        for (int k = 0; k < 16; ++k) {
            const int f = lane + 64 * k;
            float4 c = cR[k];
            float4 w = svv[f];
            float4 p;
            p.x = EXP2F(fmaf(c.x, -SV_SCALE, ui + w.x));
            p.y = EXP2F(fmaf(c.y, -SV_SCALE, ui + w.y));
            p.z = EXP2F(fmaf(c.z, -SV_SCALE, ui + w.z));
            p.w = EXP2F(fmaf(c.w, -SV_SCALE, ui + w.w));
            prow[f] = p;
            csum = fmaf(p.x, c.x, csum);
            csum = fmaf(p.y, c.y, csum);
            csum = fmaf(p.z, c.z, csum);
            csum = fmaf(p.w, c.w, csum);
        }
#pragma unroll
        for (int off = 32; off; off >>= 1) csum += __shfl_xor(csum, off);
        if (lane == 0) red2[wv] = csum;
    }
    // cost rides the final barrier payload; only the scanner needs the total.
    float ctot = grid_sync(ws, b, t, G++, red2, &bcast, false);
    if (b == 0 && t == 0) out[0] = ctot;
}

extern "C" void kernel_launch(void* const* d_in, const int* in_sizes, int n_in,
                              void* d_out, int out_size, void* d_ws, size_t ws_size,
                              hipStream_t stream) {
    const float* x = (const float*)d_in[0];  // [4096,64]
    const float* y = (const float*)d_in[1];  // [4096,64]
    float* out = (float*)d_out;              // [0]=cost, [1..N*N]=pi, [1+N*N..]=C
    float* C = out + 1 + (size_t)N * N;
    float* Ct = out;  // scratch: aliases cost+pi region, dead before final writes
    float* ws = (float*)d_ws;

    init_ws<<<dim3((WS_TOTAL + 255) / 256), dim3(256), 0, stream>>>(ws);

    dim3 bgrid(64, 64);
    build_dist<<<bgrid, dim3(256), 0, stream>>>(x, y, C);   // C[i][j]
    build_dist<<<bgrid, dim3(256), 0, stream>>>(y, x, Ct);  // C^T[j][i]

    float target = EPS * logf(1.0f / (float)N + 1e-8f);  // == eps*log_mu == eps*log_nu

    sinkhorn_persist<<<dim3(NBLK), dim3(TPB), 0, stream>>>(C, Ct, ws, out, target);
}

// Round 10
// 971.793 us; speedup vs baseline: 2.2817x; 1.5752x over previous
//
#include <hip/hip_runtime.h>
#include <math.h>

#define N 4096
#define DIM 64
#define MAX_ITER 50
#define EPS 0.1f
#define THRESH 0.1f

// exp2/log2 domain constants
#define SV_SCALE 14.4269504088896340f  // (1/eps) * log2(e)
#define EPS_LN2 0.0693147180559945f    // eps * ln(2)

// gfx950 native transcendentals: v_exp_f32 IS 2^x, v_log_f32 IS log2
#define EXP2F(x) __builtin_amdgcn_exp2f(x)
#define LOG2F(x) __builtin_amdgcn_logf(x)

// 256 blocks x 1024 threads (16 waves), wave-per-row, 16 rows/block, 1 block/CU.
// Each wave PINS its 16KB C row in 64 VGPRs for the entire kernel. BOTH phases
// now compute from the pinned registers: u-phase = row-LSE; v-phase = per-block
// column partials (LDS transpose) + cross-block (m,s) combine via 8MB of
// relaxed-agent atomics in the dead pi region. Ct is never built or streamed.
#define NBLK 256
#define TPB 1024
#define WAVES 16
#define NREP 16  // wake replicas

// ws layout (floats): v[4096] + barrier flags/replicas. u lives in registers.
#define WS_V 0
#define WS_FLAGS N                    // 256 x (u32 gen, f32 val) 8B pairs
#define WS_GGEN (N + 2 * NBLK)        // 16 replicas x 16-word stride
#define WS_TOTAL (N + 2 * NBLK + NREP * 16)

// opaque keep-alive: values become non-rematerializable register residents
#define PIN4(v) asm volatile("" : "+v"(v.x), "+v"(v.y), "+v"(v.z), "+v"(v.w))

// ---------------- init: zero v, flags, replicas ----------------
__global__ void init_ws(float* __restrict__ ws) {
    int i = blockIdx.x * 256 + threadIdx.x;
    if (i < WS_TOTAL) ws[i] = 0.0f;
}

// ---------------- build D[i][j] = sum_d (A[i][d]-B[j][d])^2 ----------------
__global__ __launch_bounds__(256) void build_dist(const float* __restrict__ A,
                                                  const float* __restrict__ B,
                                                  float* __restrict__ Dst) {
    __shared__ float As[64][68];
    __shared__ float Bs[64][68];
    const int i0 = blockIdx.y << 6, j0 = blockIdx.x << 6;
    const int t = threadIdx.x;
    const float* Ag = A + (size_t)i0 * DIM;
    const float* Bg = B + (size_t)j0 * DIM;
    for (int k = t; k < 4096; k += 256) {
        As[k >> 6][k & 63] = Ag[k];
        Bs[k >> 6][k & 63] = Bg[k];
    }
    __syncthreads();
    const int ty = t >> 4, tx = t & 15;
    float acc[4][4] = {{0.f}};
    for (int d = 0; d < DIM; d += 4) {
        float4 av[4], bv[4];
#pragma unroll
        for (int a = 0; a < 4; ++a) av[a] = *(const float4*)&As[ty + 16 * a][d];
#pragma unroll
        for (int b = 0; b < 4; ++b) bv[b] = *(const float4*)&Bs[tx + 16 * b][d];
#pragma unroll
        for (int a = 0; a < 4; ++a)
#pragma unroll
            for (int b = 0; b < 4; ++b) {
                float d0 = av[a].x - bv[b].x;
                float d1 = av[a].y - bv[b].y;
                float d2 = av[a].z - bv[b].z;
                float d3 = av[a].w - bv[b].w;
                acc[a][b] = fmaf(d0, d0, acc[a][b]);
                acc[a][b] = fmaf(d1, d1, acc[a][b]);
                acc[a][b] = fmaf(d2, d2, acc[a][b]);
                acc[a][b] = fmaf(d3, d3, acc[a][b]);
            }
    }
#pragma unroll
    for (int a = 0; a < 4; ++a) {
        int i = i0 + ty + 16 * a;
        float* drow = Dst + (size_t)i * N + j0;
#pragma unroll
        for (int b = 0; b < 4; ++b) drow[tx + 16 * b] = acc[a][b];
    }
}

// -------- grid barrier: flag-array + dedicated scanner, payload-carrying -----
__device__ __forceinline__ float grid_sync(float* ws, int b, int t, unsigned G,
                                           const float* red2, float* bcast,
                                           bool wake) {
    __syncthreads();  // red2 complete; all lanes' atomic stores retired
    if (t == 0) {
        float s = 0.f;
#pragma unroll
        for (int i = 0; i < WAVES; ++i) s += red2[i];
        unsigned long long pk = (unsigned long long)G |
                                ((unsigned long long)__float_as_uint(s) << 32);
        __hip_atomic_store((unsigned long long*)(ws + WS_FLAGS) + b, pk,
                           __ATOMIC_RELAXED, __HIP_MEMORY_SCOPE_AGENT);
    }
    if (b == 0 && t < 64) {  // scanner wave
        unsigned long long* fl = (unsigned long long*)(ws + WS_FLAGS);
        float sum;
        for (;;) {
            bool ok = true;
            sum = 0.f;
#pragma unroll
            for (int j = 0; j < NBLK / 64; ++j) {
                unsigned long long q =
                    __hip_atomic_load(fl + (t * (NBLK / 64) + j),
                                      __ATOMIC_RELAXED, __HIP_MEMORY_SCOPE_AGENT);
                ok = ok && ((unsigned)q >= G);
                sum += __uint_as_float((unsigned)(q >> 32));
            }
            if (__all(ok)) break;
            __builtin_amdgcn_s_sleep(1);
        }
#pragma unroll
        for (int off = 32; off; off >>= 1) sum += __shfl_xor(sum, off);
        if (wake && t < NREP) {
            unsigned long long pk =
                (unsigned long long)G |
                ((unsigned long long)__float_as_uint(sum) << 32);
            __hip_atomic_store((unsigned long long*)(ws + WS_GGEN) + t * 8, pk,
                               __ATOMIC_RELAXED, __HIP_MEMORY_SCOPE_AGENT);
        }
        if (t == 0) *bcast = sum;
    } else if (t == 0 && wake) {  // b != 0
        unsigned long long* gp =
            (unsigned long long*)(ws + WS_GGEN) + (b & (NREP - 1)) * 8;
        unsigned long long q;
        for (;;) {
            q = __hip_atomic_load(gp, __ATOMIC_RELAXED, __HIP_MEMORY_SCOPE_AGENT);
            if ((unsigned)q >= G) break;
            __builtin_amdgcn_s_sleep(2);
        }
        *bcast = __uint_as_float((unsigned)(q >> 32));
    }
    __syncthreads();
    return *bcast;  // valid when wake (all blocks) or b==0
}

// ------- stage the v vector into LDS, pre-scaled to exp2 domain -------
__device__ __forceinline__ void stage(const float* __restrict__ src,
                                      float* __restrict__ sv, int t) {
    const unsigned long long* s8 = (const unsigned long long*)src;
#pragma unroll
    for (int i = 0; i < 2; ++i) {
        int idx = t + TPB * i;  // 0..2047
        unsigned long long q = __hip_atomic_load(s8 + idx, __ATOMIC_RELAXED,
                                                 __HIP_MEMORY_SCOPE_AGENT);
        sv[2 * idx] = __uint_as_float((unsigned)q) * SV_SCALE;
        sv[2 * idx + 1] = __uint_as_float((unsigned)(q >> 32)) * SV_SCALE;
    }
}

// ---- u-phase: row LSE from the PINNED register row (zero memory traffic) ----
// Returns u_new on ALL lanes (shuffle reduction converges).
__device__ __forceinline__ float phasePinned(const float4 (&cR)[16],
                                             const float* __restrict__ sv,
                                             int lane, float target) {
    const float4* __restrict__ svv = (const float4*)sv;
    float m = -3.0e38f, s = 0.f;
#pragma unroll
    for (int g = 0; g < 4; ++g) {
        float d[16];
#pragma unroll
        for (int k = 0; k < 4; ++k) {
            float4 w = svv[lane + 64 * (4 * g + k)];
            d[4 * k + 0] = fmaf(cR[4 * g + k].x, -SV_SCALE, w.x);
            d[4 * k + 1] = fmaf(cR[4 * g + k].y, -SV_SCALE, w.y);
            d[4 * k + 2] = fmaf(cR[4 * g + k].z, -SV_SCALE, w.z);
            d[4 * k + 3] = fmaf(cR[4 * g + k].w, -SV_SCALE, w.w);
        }
        float m4[4];
#pragma unroll
        for (int k = 0; k < 4; ++k)
            m4[k] = fmaxf(fmaxf(d[4 * k], d[4 * k + 1]),
                          fmaxf(d[4 * k + 2], d[4 * k + 3]));
        float mg = fmaxf(fmaxf(m4[0], m4[1]), fmaxf(m4[2], m4[3]));
        float mn = fmaxf(m, mg);
        float ps = 0.f;
#pragma unroll
        for (int k = 0; k < 16; ++k) ps += EXP2F(d[k] - mn);
        s = fmaf(s, EXP2F(m - mn), ps);
        m = mn;
    }
#pragma unroll
    for (int off = 32; off; off >>= 1) {
        float mo = __shfl_xor(m, off);
        float so = __shfl_xor(s, off);
        float mn = fmaxf(m, mo);
        s = fmaf(s, EXP2F(m - mn), so * EXP2F(mo - mn));
        m = mn;
    }
    return fmaf(-EPS_LN2, m + LOG2F(s), target);
}

// ---------------- persistent kernel: all iterations + final ----------------
__global__ __launch_bounds__(TPB)
__attribute__((amdgpu_waves_per_eu(4, 4)))  // authorize the 128-VGPR tier
void sinkhorn_persist(
    const float* __restrict__ Cm, float* __restrict__ ws,
    float* __restrict__ out, float target) {
    __shared__ float sv[N];                // 16 KB staged (scaled) v
    __shared__ float4 bufv[WAVES][256];    // 64 KB transpose buffer
    __shared__ float us_lds[WAVES];        // this block's 16 scaled-u values
    __shared__ float red2[WAVES];
    __shared__ float bcast;
    float* v = ws + WS_V;
    unsigned long long* P8 = (unsigned long long*)(out + 1);  // 8MB partials
    const int t = threadIdx.x;
    const int b = blockIdx.x;
    const int lane = t & 63, wv = t >> 6;
    const int row = (b << 4) + wv;  // this wave's row
    unsigned G = 1;
    float errv = 1e30f;
    float uprev = 0.f, un = 0.f;

    // prologue: load this wave's C row ONCE; pin it for the whole kernel.
    float4 cR[16];
    {
        const float4* __restrict__ crow = (const float4*)(Cm + (size_t)row * N);
#pragma unroll
        for (int k = 0; k < 16; ++k) cR[k] = crow[lane + 64 * k];
#pragma unroll
        for (int k = 0; k < 16; ++k) PIN4(cR[k]);
    }

    for (int it = 0; it < MAX_ITER; ++it) {
        // ---- u-phase: zero memory traffic ----
        stage(v, sv, t);
        __syncthreads();
        un = phasePinned(cR, sv, lane, target);
        if (lane == 0) {
            red2[wv] = fabsf(un - uprev);       // err contribution
            us_lds[wv] = un * SV_SCALE;         // share u with block
        }
        uprev = un;
        __syncthreads();
        const float usw = us_lds[wv];

        // ---- v-partials: LDS transpose of register rows, per-block (m,s) ----
        for (int c = 0; c < 4; ++c) {
#pragma unroll
            for (int kk = 0; kk < 4; ++kk) {
                float4 cc = cR[4 * c + kk];
                float4 dd;
                dd.x = fmaf(cc.x, -SV_SCALE, usw);
                dd.y = fmaf(cc.y, -SV_SCALE, usw);
                dd.z = fmaf(cc.z, -SV_SCALE, usw);
                dd.w = fmaf(cc.w, -SV_SCALE, usw);
                bufv[wv][lane + 64 * kk] = dd;
            }
            __syncthreads();
            {
                const float* bufs = (const float*)bufv;
                float val[16];
#pragma unroll
                for (int w2 = 0; w2 < 16; ++w2) val[w2] = bufs[w2 * 1024 + t];
                float m = val[0];
#pragma unroll
                for (int w2 = 1; w2 < 16; ++w2) m = fmaxf(m, val[w2]);
                float s = 0.f;
#pragma unroll
                for (int w2 = 0; w2 < 16; ++w2) s += EXP2F(val[w2] - m);
                const int j = c * 1024 + t;  // this thread's column
                unsigned long long pk =
                    (unsigned long long)__float_as_uint(m) |
                    ((unsigned long long)__float_as_uint(s) << 32);
                __hip_atomic_store(
                    P8 + ((size_t)(j >> 4) * NBLK + b) * 16 + (j & 15), pk,
                    __ATOMIC_RELAXED, __HIP_MEMORY_SCOPE_AGENT);
            }
            __syncthreads();
        }
        errv = grid_sync(ws, b, t, G++, red2, &bcast, true);  // partials visible

        // ---- v-combine: block b owns columns 16b..16b+15; wave wv = col jl=wv
        {
            float m = -3.0e38f, s = 0.f;
#pragma unroll
            for (int i = 0; i < 4; ++i) {
                const int bb = lane + 64 * i;
                unsigned long long q = __hip_atomic_load(
                    P8 + ((size_t)b * NBLK + bb) * 16 + wv, __ATOMIC_RELAXED,
                    __HIP_MEMORY_SCOPE_AGENT);
                float mo = __uint_as_float((unsigned)q);
                float so = __uint_as_float((unsigned)(q >> 32));
                float mn = fmaxf(m, mo);
                s = fmaf(s, EXP2F(m - mn), so * EXP2F(mo - mn));
                m = mn;
            }
#pragma unroll
            for (int off = 32; off; off >>= 1) {
                float mo = __shfl_xor(m, off);
                float so = __shfl_xor(s, off);
                float mn = fmaxf(m, mo);
                s = fmaf(s, EXP2F(m - mn), so * EXP2F(mo - mn));
                m = mn;
            }
            if (lane == 0) {
                float vn = fmaf(-EPS_LN2, m + LOG2F(s), target);
                __hip_atomic_store(&v[16 * b + wv], vn, __ATOMIC_RELAXED,
                                   __HIP_MEMORY_SCOPE_AGENT);
                red2[wv] = 0.f;
            }
        }
        grid_sync(ws, b, t, G++, red2, &bcast, true);  // v visible everywhere
        // reference latches done AFTER applying this iteration's updates.
        if (errv < THRESH) break;  // uniform: same published value everywhere
    }

    // ---- final: pi = exp((u_i + v_j - C_ij)/eps), cost = sum(pi*C) ----
    // cR pinned; un is this wave's final u (all lanes). Partials region is
    // dead; pi writes (plain stores) overwrite out[1..N^2).
    stage(v, sv, t);
    __syncthreads();
    {
        float* pi = out + 1;
        const float ui = un * SV_SCALE;  // exp2-domain
        float4* __restrict__ prow = (float4*)(pi + (size_t)row * N);
        const float4* __restrict__ svv = (const float4*)sv;
        float csum = 0.f;
#pragma unroll
        for (int k = 0; k < 16; ++k) {
            const int f = lane + 64 * k;
            float4 c = cR[k];
            float4 w = svv[f];
            float4 p;
            p.x = EXP2F(fmaf(c.x, -SV_SCALE, ui + w.x));
            p.y = EXP2F(fmaf(c.y, -SV_SCALE, ui + w.y));
            p.z = EXP2F(fmaf(c.z, -SV_SCALE, ui + w.z));
            p.w = EXP2F(fmaf(c.w, -SV_SCALE, ui + w.w));
            prow[f] = p;
            csum = fmaf(p.x, c.x, csum);
            csum = fmaf(p.y, c.y, csum);
            csum = fmaf(p.z, c.z, csum);
            csum = fmaf(p.w, c.w, csum);
        }
#pragma unroll
        for (int off = 32; off; off >>= 1) csum += __shfl_xor(csum, off);
        if (lane == 0) red2[wv] = csum;
    }
    // cost rides the final barrier payload; only the scanner needs the total.
    float ctot = grid_sync(ws, b, t, G++, red2, &bcast, false);
    if (b == 0 && t == 0) out[0] = ctot;
}

extern "C" void kernel_launch(void* const* d_in, const int* in_sizes, int n_in,
                              void* d_out, int out_size, void* d_ws, size_t ws_size,
                              hipStream_t stream) {
    const float* x = (const float*)d_in[0];  // [4096,64]
    const float* y = (const float*)d_in[1];  // [4096,64]
    float* out = (float*)d_out;              // [0]=cost, [1..N*N]=pi, [1+N*N..]=C
    float* C = out + 1 + (size_t)N * N;
    float* ws = (float*)d_ws;

    init_ws<<<dim3((WS_TOTAL + 255) / 256), dim3(256), 0, stream>>>(ws);

    dim3 bgrid(64, 64);
    build_dist<<<bgrid, dim3(256), 0, stream>>>(x, y, C);  // C[i][j] only; no Ct

    float target = EPS * logf(1.0f / (float)N + 1e-8f);  // == eps*log_mu == eps*log_nu

    sinkhorn_persist<<<dim3(NBLK), dim3(TPB), 0, stream>>>(C, ws, out, target);
}